// Round 1
// 288.385 us; speedup vs baseline: 1.0686x; 1.0686x over previous
//
#include <hip/hip_runtime.h>
#include <cstdint>
#include <cfloat>

#define BATCH 16
#define NBOX 25200
#define CH 85
#define NCLS 80
#define CAP 512
#define SEGCAP 128   // CAP/4, per-sub-counter capacity (mean occupancy ~59)
#define ACC 48
#define MAXDET 300
#define RPB 112      // rows per block: 38,080 B LDS -> 4 blocks/CU (was 3 at 128)
#define CNTPAD 16    // ints per counter slot (64B line); segs 0..3 live in one line

typedef unsigned long long u64;

__device__ __forceinline__ u64 shflx64(u64 v, int m) {
    int lo = __shfl_xor((int)(unsigned)(v & 0xffffffffu), m);
    int hi = __shfl_xor((int)(unsigned)(v >> 32), m);
    return ((u64)(unsigned)hi << 32) | (u64)(unsigned)lo;
}

// ---------------- kernel A: staged per-row conf/argmax + bucket by (image,class)
// Segmented counters: 4 sub-counters per bucket (idx&3) cut the same-address
// atomic chain 236 -> ~59. Also zeroes the output tensor (folds the out-memset).
__global__ __launch_bounds__(256) void pre_kernel(const float* __restrict__ p,
                                                  int* __restrict__ cnt,
                                                  u64* __restrict__ bucketKey,
                                                  float* __restrict__ outZero,
                                                  int outN) {
#pragma clang fp contract(off)
    __shared__ float s[RPB * CH];          // 38,080 B
    int tid = threadIdx.x;

    // fold hipMemsetAsync(out): first 132 blocks store one zero each-thread
    long z = (long)blockIdx.x * 256 + tid;
    if (z < outN) outZero[z] = 0.0f;

    long blockRow = (long)blockIdx.x * RPB;

    // async global->LDS staging, 16B/lane, lane-contiguous (wave-uniform base + lane*16)
    const float4* p4 = (const float4*)(p + blockRow * CH);
    float4* s4 = (float4*)s;
    for (int t = tid; t < RPB * CH / 4; t += 256) {
        __builtin_amdgcn_global_load_lds(
            (const __attribute__((address_space(1))) void*)(p4 + t),
            (__attribute__((address_space(3))) void*)(s4 + (t & ~63)),
            16, 0, 0);
    }
    __syncthreads();

    int r = tid >> 1;                      // row 0..127 (only <RPB valid)
    int half = tid & 1;                    // classes [0,40) vs [40,80)
    if (r < RPB) {
        const float* row = s + r * CH;
        float obj = row[4];

        float v = -FLT_MAX; int c = 1000;
        int c0 = half * 40;
        for (int k = 0; k < 40; k++) {
            float sc = row[5 + c0 + k] * obj;  // multiply-first, matches reference
            int cc = c0 + k;
            if (sc > v) { v = sc; c = cc; }    // strict > keeps first max
        }
        float v2 = __shfl_xor(v, 1);
        int   cz = __shfl_xor(c, 1);
        if (v2 > v || (v2 == v && cz < c)) { v = v2; c = cz; }

        if (half == 0 && obj > 0.25f && v > 0.25f) {
            int wid = (int)blockRow + r;
            int b   = wid / NBOX;
            int idx = wid - b * NBOX;          // < 25200 < 2^15
            u64 key = ((u64)__float_as_uint(v) << 22) | ((u64)(32767 - idx) << 7) | (u64)c;
            int bkt = b * NCLS + c;
            int seg = idx & 3;
            int pos = atomicAdd(&cnt[bkt * CNTPAD + seg], 1);
            if (pos < SEGCAP) bucketKey[(long)bkt * CAP + seg * SEGCAP + pos] = key;
        }
    }
}

// ---------------- kernel B: wave-per-bucket register-resident greedy NMS -------
__global__ __launch_bounds__(256) void nms_kernel(const float* __restrict__ p,
                                                  const int* __restrict__ cnt,
                                                  const u64* __restrict__ bucketKey,
                                                  u64* __restrict__ accKey) {
#pragma clang fp contract(off)
    int lane = threadIdx.x & 63;
    int bkt = (blockIdx.x << 2) | (threadIdx.x >> 6);
    int b = bkt / NCLS, c = bkt - b * NCLS;

    const int* cb = cnt + bkt * CNTPAD;
    int ns[4];
#pragma unroll
    for (int s2 = 0; s2 < 4; s2++) {
        int v = cb[s2];
        ns[s2] = (v < SEGCAP) ? v : SEGCAP;
    }
    int ntot = ns[0] + ns[1] + ns[2] + ns[3];

    // linear slot pos == seg*SEGCAP + off, so addresses are unchanged;
    // validity is per-segment: off = ((r&1)<<6)|lane, seg = r>>1 (compile-time).
    u64 key[8];
#pragma unroll
    for (int r = 0; r < 8; r++) {
        int off = ((r & 1) << 6) | lane;
        key[r] = (off < ns[r >> 1]) ? bucketKey[(long)bkt * CAP + (r << 6) + lane] : 0ULL;
    }

    auto CE_lane = [&](int k, int j) {
#pragma unroll
        for (int r = 0; r < 8; r++) {
            u64 part = shflx64(key[r], j);
            int pos = (r << 6) | lane;
            bool keepmax = (((pos & k) == 0) == ((lane & j) == 0));
            u64 mx = (key[r] > part) ? key[r] : part;
            u64 mn = (key[r] > part) ? part : key[r];
            key[r] = keepmax ? mx : mn;
        }
    };

#pragma unroll
    for (int k = 2; k <= 64; k <<= 1)
        for (int j = k >> 1; j > 0; j >>= 1)
            CE_lane(k, j);

#define CE_REG(K, M)                                                   \
    {                                                                  \
        _Pragma("unroll")                                              \
        for (int r = 0; r < 8; r++) if (!(r & (M))) {                  \
            int r2 = r | (M);                                          \
            u64 a = key[r], d = key[r2];                               \
            bool desc = (((r << 6) & (K)) == 0);                       \
            u64 hi = (a > d) ? a : d, lo = (a > d) ? d : a;            \
            key[r]  = desc ? hi : lo;                                  \
            key[r2] = desc ? lo : hi;                                  \
        }                                                              \
    }

    CE_REG(128, 1)
    for (int j = 32; j > 0; j >>= 1) CE_lane(128, j);
    CE_REG(256, 2) CE_REG(256, 1)
    for (int j = 32; j > 0; j >>= 1) CE_lane(256, j);
    CE_REG(512, 4) CE_REG(512, 2) CE_REG(512, 1)
    for (int j = 32; j > 0; j >>= 1) CE_lane(512, j);
#undef CE_REG

    // after the descending sort all valid (nonzero) keys occupy pos < ntot
    float off = (float)c * 4096.0f;
    float rx1[8], ry1[8], rx2[8], ry2[8], rar[8];
    int live = 0;
#pragma unroll
    for (int r = 0; r < 8; r++) {
        int pos = (r << 6) | lane;
        rx1[r] = 0.f; ry1[r] = 0.f; rx2[r] = 0.f; ry2[r] = 0.f; rar[r] = 0.f;
        if (pos < ntot) {
            int idx = 32767 - (int)((key[r] >> 7) & 32767);
            const float* q = p + ((long)b * NBOX + idx) * CH;
            float x = q[0], y = q[1], w = q[2], h = q[3];
            float hw = w * 0.5f, hh = h * 0.5f;
            rx1[r] = (x - hw) + off; ry1[r] = (y - hh) + off;
            rx2[r] = (x + hw) + off; ry2[r] = (y + hh) + off;
            rar[r] = (rx2[r] - rx1[r]) * (ry2[r] - ry1[r]);
            live |= 1 << r;
        }
    }

    long obase = (long)bkt * ACC;
    int nacc = 0;
    for (;;) {
        // find first live position; i is wave-uniform so the early-out branch
        // is exec-uniform and skips the remaining ballots
        int i = -1;
#pragma unroll
        for (int r = 0; r < 8; r++) {
            if (i < 0) {
                u64 mr = __ballot((live >> r) & 1);
                if (mr) i = (r << 6) + (int)__ffsll((long long)mr) - 1;
            }
        }
        if (i < 0) break;
        int ro = i >> 6, owner = i & 63;

        u64 kk; float sX1, sY1, sX2, sY2, sA;
        switch (ro) {
            case 0: kk=key[0]; sX1=rx1[0]; sY1=ry1[0]; sX2=rx2[0]; sY2=ry2[0]; sA=rar[0]; break;
            case 1: kk=key[1]; sX1=rx1[1]; sY1=ry1[1]; sX2=rx2[1]; sY2=ry2[1]; sA=rar[1]; break;
            case 2: kk=key[2]; sX1=rx1[2]; sY1=ry1[2]; sX2=rx2[2]; sY2=ry2[2]; sA=rar[2]; break;
            case 3: kk=key[3]; sX1=rx1[3]; sY1=ry1[3]; sX2=rx2[3]; sY2=ry2[3]; sA=rar[3]; break;
            case 4: kk=key[4]; sX1=rx1[4]; sY1=ry1[4]; sX2=rx2[4]; sY2=ry2[4]; sA=rar[4]; break;
            case 5: kk=key[5]; sX1=rx1[5]; sY1=ry1[5]; sX2=rx2[5]; sY2=ry2[5]; sA=rar[5]; break;
            case 6: kk=key[6]; sX1=rx1[6]; sY1=ry1[6]; sX2=rx2[6]; sY2=ry2[6]; sA=rar[6]; break;
            default:kk=key[7]; sX1=rx1[7]; sY1=ry1[7]; sX2=rx2[7]; sY2=ry2[7]; sA=rar[7]; break;
        }
        if (lane == owner) {
            accKey[obase + nacc] = kk;
            live &= ~(1 << ro);
        }
        nacc++;
        if (nacc == ACC) break;

        // broadcast owner's box via v_readlane (exec-independent, no LDS trip)
        float X1 = __int_as_float(__builtin_amdgcn_readlane(__float_as_int(sX1), owner));
        float Y1 = __int_as_float(__builtin_amdgcn_readlane(__float_as_int(sY1), owner));
        float X2 = __int_as_float(__builtin_amdgcn_readlane(__float_as_int(sX2), owner));
        float Y2 = __int_as_float(__builtin_amdgcn_readlane(__float_as_int(sY2), owner));
        float A  = __int_as_float(__builtin_amdgcn_readlane(__float_as_int(sA),  owner));

#pragma unroll
        for (int r = 0; r < 8; r++) {
            if ((live >> r) & 1) {
                float xx1 = fmaxf(X1, rx1[r]);
                float yy1 = fmaxf(Y1, ry1[r]);
                float xx2 = fminf(X2, rx2[r]);
                float yy2 = fminf(Y2, ry2[r]);
                float inter = fmaxf(xx2 - xx1, 0.0f) * fmaxf(yy2 - yy1, 0.0f);
                float uni = (A + rar[r]) - inter;
                if (inter / uni > 0.45f) live &= ~(1 << r);
            }
        }
    }
    for (int t = nacc + lane; t < ACC; t += 64) accKey[obase + t] = 0ULL;
}

// ---------------- kernel C: rank-based merge, no sort, no barriers -------------
// rank(key) = own_pos + sum over other classes of count(entries > key).
// 4 classes searched concurrently: 4 independent 6-step ds_read_b64 chains in
// flight instead of one (pure LDS-latency phase -> ~4x).
__global__ __launch_bounds__(256) void merge_kernel(const float* __restrict__ p,
                                                    const u64* __restrict__ accKey,
                                                    float* __restrict__ outRows,
                                                    float* __restrict__ outKeep) {
#pragma clang fp contract(off)
    __shared__ u64 L[NCLS * ACC];          // 30,720 B
    int tid = threadIdx.x;
    int b = blockIdx.y;
    const u64* src = accKey + (long)b * NCLS * ACC;
    for (int t = tid; t < NCLS * ACC; t += 256) L[t] = src[t];
    __syncthreads();

    int g = blockIdx.x * 256 + tid;        // 0..3839
    u64 key = L[g];
    if (key == 0ULL) return;
    int cOwn = g / ACC;
    int rank = g - cOwn * ACC;             // entries before me in my (desc) list are > me

    int d = 1;
    for (; d + 3 < NCLS; d += 4) {
        int ca = cOwn + d;     if (ca >= NCLS) ca -= NCLS;
        int cb = cOwn + d + 1; if (cb >= NCLS) cb -= NCLS;
        int cc = cOwn + d + 2; if (cc >= NCLS) cc -= NCLS;
        int cd = cOwn + d + 3; if (cd >= NCLS) cd -= NCLS;
        const u64* LA = L + ca * ACC;      // each sorted desc, zero-padded
        const u64* LB = L + cb * ACC;
        const u64* LC = L + cc * ACC;
        const u64* LD = L + cd * ACC;
        int na = 0, nb = 0, nc = 0, nd = 0;
#pragma unroll
        for (int s2 = 32; s2; s2 >>= 1) {
            int ta = na + s2, tb = nb + s2, tc = nc + s2, td = nd + s2;
            if (ta <= ACC && LA[ta - 1] > key) na = ta;
            if (tb <= ACC && LB[tb - 1] > key) nb = tb;
            if (tc <= ACC && LC[tc - 1] > key) nc = tc;
            if (td <= ACC && LD[td - 1] > key) nd = td;
        }
        rank += na + nb + nc + nd;
        if (rank >= MAXDET) return;        // rank only grows; prune
    }
    for (; d < NCLS; d++) {
        int c2 = cOwn + d; if (c2 >= NCLS) c2 -= NCLS;
        const u64* Lc = L + c2 * ACC;
        int cn = 0;
#pragma unroll
        for (int s2 = 32; s2; s2 >>= 1) {
            int ncx = cn + s2;
            if (ncx <= ACC && Lc[ncx - 1] > key) cn = ncx;
        }
        rank += cn;
        if (rank >= MAXDET) return;
    }

    int cc  = (int)(key & 127);
    int idx = 32767 - (int)((key >> 7) & 32767);
    float conf = __uint_as_float((unsigned)(key >> 22));
    const float* q = p + ((long)b * NBOX + idx) * CH;
    float x = q[0], y = q[1], w = q[2], h = q[3];
    float hw = w * 0.5f, hh = h * 0.5f;
    float* row = outRows + ((long)b * MAXDET + rank) * 6;
    row[0] = x - hw; row[1] = y - hh; row[2] = x + hw; row[3] = y + hh;
    row[4] = conf;   row[5] = (float)cc;
    outKeep[b * MAXDET + rank] = 1.0f;
}

extern "C" void kernel_launch(void* const* d_in, const int* in_sizes, int n_in,
                              void* d_out, int out_size, void* d_ws, size_t ws_size,
                              hipStream_t stream) {
    const float* p = (const float*)d_in[0];
    float* out = (float*)d_out;

    char* ws = (char*)d_ws;
    int* cnt = (int*)ws;                                   // 1280 * 64B padded counters
    u64* bucketKey = (u64*)(ws + BATCH * NCLS * CNTPAD * 4);               // 5.24 MB
    u64* accKey    = (u64*)(ws + BATCH * NCLS * CNTPAD * 4
                               + (size_t)BATCH * NCLS * CAP * 8);          // 491 KB

    hipMemsetAsync(cnt, 0, BATCH * NCLS * CNTPAD * sizeof(int), stream);
    // out zeroing folded into pre_kernel (saves one fill dispatch)
    pre_kernel<<<(BATCH * NBOX) / RPB, 256, 0, stream>>>(p, cnt, bucketKey, out, out_size);
    nms_kernel<<<BATCH * NCLS / 4, 256, 0, stream>>>(p, cnt, bucketKey, accKey);
    dim3 gM(NCLS * ACC / 256, BATCH);
    merge_kernel<<<gM, 256, 0, stream>>>(p, accKey, out, out + (size_t)BATCH * MAXDET * 6);
}